// Round 2
// baseline (5531.440 us; speedup 1.0000x reference)
//
#include <hip/hip_runtime.h>
#include <math.h>

// PEPS amplitude via boundary-MPS contraction, fully fused in one kernel.
// Lx=Ly=10, PHYS=2, D=4, CHI=4. Two teams (2 waves): team0 = bottom half,
// team1 = top half (identical shape sequences -> lockstep barriers).
// All decompositions (MGS-QR, Gram+parallel-Jacobi SVD) in fp64; tensors fp32.

#define NS 10

__device__ __forceinline__ double shfl_d(double x, int src) {
  union { double d; int i[2]; } u;
  u.d = x;
  u.i[0] = __shfl(u.i[0], src, 64);
  u.i[1] = __shfl(u.i[1], src, 64);
  return u.d;
}
__device__ __forceinline__ double shflx_d(double x, int m) {
  union { double d; int i[2]; } u;
  u.d = x;
  u.i[0] = __shfl_xor(u.i[0], m, 64);
  u.i[1] = __shfl_xor(u.i[1], m, 64);
  return u.d;
}
__device__ __forceinline__ double wsum64(double x) {
#pragma unroll
  for (int o = 1; o < 64; o <<= 1) x += shflx_d(x, o);
  return x;
}
#define SEL4(a, k) ((k) == 1 ? (a)[1] : (k) == 2 ? (a)[2] : (k) == 3 ? (a)[3] : (a)[0])

// Two-sided parallel Jacobi eigensolver on a (padded) 16x16 symmetric PSD
// matrix. Layout: lane = i*4 + j4 holds G[i][4*j4..4*j4+3] and Vt[i][...]
// (Vt = V^T, so eigvec idx is row idx of Vt). info[t][idx] packs:
// partner(5b) | pairslot(3b) | sideP(1b) | active(1b). No barriers inside.
__device__ void jacobi_sym(double* gw, double* vtw, double* ev, int lane,
                           const int (*info)[16], const int (*pqt)[8],
                           int nrounds, int maxsweep) {
  const int i = lane >> 2, j4 = lane & 3;
  double g[4], v[4];
#pragma unroll
  for (int cc = 0; cc < 4; ++cc) {
    g[cc] = gw[i * 16 + j4 * 4 + cc];
    v[cc] = (i == j4 * 4 + cc) ? 1.0 : 0.0;
  }
  for (int sw = 0; sw < maxsweep; ++sw) {
    double off = 0.0, dsq = 0.0;
#pragma unroll
    for (int cc = 0; cc < 4; ++cc) {
      double gv = g[cc];
      if (j4 * 4 + cc == i) dsq += gv * gv; else off += gv * gv;
    }
    off = wsum64(off); dsq = wsum64(dsq);
    if (off <= dsq * 1e-26) break;  // converged (uniform within wave)
    for (int t = 0; t < nrounds; ++t) {
      int mi = info[t][i];
      int mpart = mi & 31;
      int mpidx = (mi >> 5) & 7;
      double msgn = ((mi >> 8) & 1) ? -1.0 : 1.0;
      bool mact = ((mi >> 9) & 1) != 0;
      int civ[4];
      civ[0] = info[t][j4 * 4 + 0];
      civ[1] = info[t][j4 * 4 + 1];
      civ[2] = info[t][j4 * 4 + 2];
      civ[3] = info[t][j4 * 4 + 3];
      // provider-side extracts (pre-round values)
      double dsel = SEL4(g, i & 3);        // valid on diag holders
      double psel = SEL4(g, mpart & 3);    // valid on (i, partner(i)) holders
      // rotation params: lane m computes pair m (redundant in upper lanes)
      int pq = pqt[t][lane & 7];
      int P = pq & 255, Q = pq >> 8;
      double app = shfl_d(dsel, P * 4 + (P >> 2));
      double apq = shfl_d(psel, P * 4 + (Q >> 2));
      double aqq = shfl_d(dsel, Q * 4 + (Q >> 2));
      bool z = fabs(apq) < 1e-300;
      double tau = (aqq - app) / (z ? 1.0 : (2.0 * apq));
      double tt = copysign(1.0, tau) / (fabs(tau) + sqrt(1.0 + tau * tau));
      double c1 = 1.0 / sqrt(1.0 + tt * tt);
      double s1 = tt * c1;
      if (z) { c1 = 1.0; s1 = 0.0; }
      // --- G column phase: fetch (i, partner(col)) pre-update ---
      double oth[4];
      int rowbase = (lane >> 2) << 2;
#pragma unroll
      for (int cc = 0; cc < 4; ++cc) {
        int pc = civ[cc] & 31;
        int src = rowbase + (pc >> 2);
        double t0 = shfl_d(g[0], src);
        double t1 = shfl_d(g[1], src);
        double t2 = shfl_d(g[2], src);
        double t3 = shfl_d(g[3], src);
        int rs = pc & 3;
        double o_ = t0; o_ = (rs == 1) ? t1 : o_;
        o_ = (rs == 2) ? t2 : o_; o_ = (rs == 3) ? t3 : o_;
        oth[cc] = o_;
      }
#pragma unroll
      for (int cc = 0; cc < 4; ++cc) {
        int cinf = civ[cc];
        int cp = (cinf >> 5) & 7;
        double cr = shfl_d(c1, cp);
        double sr = shfl_d(s1, cp);
        double sg = ((cinf >> 8) & 1) ? -sr : sr;
        double gn = cr * g[cc] + sg * oth[cc];
        g[cc] = (((cinf >> 9) & 1) != 0) ? gn : g[cc];
      }
      // --- G row phase + Vt row phase (post-column values) ---
      double myc = shfl_d(c1, mpidx);
      double mys = shfl_d(s1, mpidx);
      double sg2 = msgn * mys;
      int srow = mpart * 4 + j4;
      double og[4], ov[4];
#pragma unroll
      for (int cc = 0; cc < 4; ++cc) og[cc] = shfl_d(g[cc], srow);
#pragma unroll
      for (int cc = 0; cc < 4; ++cc) ov[cc] = shfl_d(v[cc], srow);
#pragma unroll
      for (int cc = 0; cc < 4; ++cc) {
        double gn = myc * g[cc] + sg2 * og[cc];
        double vn = myc * v[cc] + sg2 * ov[cc];
        g[cc] = mact ? gn : g[cc];
        v[cc] = mact ? vn : v[cc];
      }
    }
  }
#pragma unroll
  for (int cc = 0; cc < 4; ++cc) vtw[i * 16 + j4 * 4 + cc] = v[cc];
  if ((i >> 2) == j4) ev[i] = SEL4(g, i & 3);
}

__global__ __launch_bounds__(128, 1)
void amp_kernel(const float* __restrict__ peps, const int* __restrict__ xs,
                float* __restrict__ out) {
  const int tid = threadIdx.x;
  const int team = tid >> 6;      // 0 = bottom half, 1 = top half
  const int lane = tid & 63;

  __shared__ __align__(16) float Ash[2][NS][1024];  // MPS tensors (l,r,4)
  __shared__ __align__(16) float Tmp[2][1024];      // staging
  __shared__ __align__(16) float Tsh[2][256];       // site tensor T (4,4,4,4)
  __shared__ double Rw[2][256];                     // QR R (16x16)
  __shared__ double Gw[2][256];                     // Gram (16x16, zero-pad)
  __shared__ double Vt[2][256];                     // eigvecs, Vt[idx][a]
  __shared__ double USw[2][64];                     // U[:, :k]*S[:k] (l x 4)
  __shared__ double evals[2][16];
  __shared__ int dL[2][NS], dR[2][NS];
  __shared__ double lz[2];
  __shared__ double vbuf[2][16];
  __shared__ int jt16_info[15][16];
  __shared__ int jt16_PQ[15][8];
  __shared__ int jt4_info[3][16];
  __shared__ int jt4_PQ[3][8];

  float (*A)[1024] = Ash[team];
  float* tmp = Tmp[team];
  float* tsh = Tsh[team];
  double* rw = Rw[team];
  double* gw = Gw[team];
  double* vt = Vt[team];
  double* usw = USw[team];
  double* ev = evals[team];
  int* dl = dL[team];
  int* dr = dR[team];

  // ---- build round-robin Jacobi schedules (shared, data-independent) ----
  if (tid < 15) {
    int t = tid;
    int pos[16];
    pos[0] = 0;
#pragma unroll
    for (int q = 1; q < 16; ++q) pos[q] = 1 + (q - 1 + t) % 15;
#pragma unroll
    for (int m = 0; m < 8; ++m) {
      int a = pos[m], b = pos[15 - m];
      int P = a < b ? a : b, Q = a < b ? b : a;
      jt16_PQ[t][m] = P | (Q << 8);
      jt16_info[t][P] = Q | (m << 5) | (1 << 8) | (1 << 9);
      jt16_info[t][Q] = P | (m << 5) | (1 << 9);
    }
  }
  if (tid >= 32 && tid < 35) {
    int t = tid - 32;
    int pos[4];
    pos[0] = 0;
#pragma unroll
    for (int q = 1; q < 4; ++q) pos[q] = 1 + (q - 1 + t) % 3;
    for (int q = 0; q < 16; ++q) jt4_info[t][q] = 0;  // inactive
#pragma unroll
    for (int m = 0; m < 2; ++m) {
      int a = pos[m], b = pos[3 - m];
      int P = a < b ? a : b, Q = a < b ? b : a;
      jt4_PQ[t][m] = P | (Q << 8);
      jt4_info[t][P] = Q | (m << 5) | (1 << 8) | (1 << 9);
      jt4_info[t][Q] = P | (m << 5) | (1 << 9);
    }
#pragma unroll
    for (int m = 2; m < 8; ++m) jt4_PQ[t][m] = 0;
  }
  __syncthreads();

  double logZ = 0.0;

  // ---- init boundary row (bot: row 0, down=0; top: row 9, up=0) ----
  {
    int row0 = team ? 9 : 0;
    for (int j = 0; j < NS; ++j) {
      int p = xs[row0 * 10 + j];
      const float* tp = peps + ((size_t)(row0 * 10 + j) * 2 + p) * 256;
      ((float4*)tsh)[lane] = ((const float4*)tp)[lane];
      __syncthreads();
      int lgLt = (j == 0) ? 0 : 2, lgRt = (j == 9) ? 0 : 2;
      int Lt = 1 << lgLt, Rt = 1 << lgRt;
      int n = Lt * Rt * 4;
      if (lane < n) {
        int ui = lane & 3, h = lane >> 2;
        int ri = h & (Rt - 1), li = h >> lgRt;
        // bot: B[l,r,u] = T[u,r,0,l]; top: B[l,r,d] = T[0,r,d,l]
        float val = team ? tsh[ri * 16 + ui * 4 + li]
                         : tsh[ui * 64 + ri * 16 + li];
        A[j][lane] = val;
      }
      if (lane == 0) { dl[j] = Lt; dr[j] = Rt; }
      __syncthreads();
    }
  }

  // ---- 4 rounds of absorb + compress ----
  for (int it = 0; it < 4; ++it) {
    int row = team ? (8 - it) : (1 + it);

    // absorb row into MPS
    for (int j = 0; j < NS; ++j) {
      int p = xs[row * 10 + j];
      const float* tp = peps + ((size_t)(row * 10 + j) * 2 + p) * 256;
      ((float4*)tsh)[lane] = ((const float4*)tp)[lane];
      int l = dl[j], r = dr[j];
      int nb = l * r * 4;
      for (int o = lane; o < nb; o += 64) tmp[o] = A[j][o];
      __syncthreads();
      int lgLt = (j == 0) ? 0 : 2, lgRt = (j == 9) ? 0 : 2;
      int lp = l << lgLt, rp = r << lgRt;
      int lgrp = 31 - __clz(rp);
      int n = lp * rp * 4;
      for (int o = lane; o < n; o += 64) {
        int U = o & 3;
        int h = o >> 2;
        int ro = h & (rp - 1), lo = h >> lgrp;
        int li = lo >> lgLt, Li = lo & ((1 << lgLt) - 1);
        int ri = ro >> lgRt, Ri = ro & ((1 << lgRt) - 1);
        double acc = 0.0;
#pragma unroll
        for (int w = 0; w < 4; ++w) {
          float b = tmp[(li * r + ri) * 4 + w];
          // bot: T[U,R,w,L]; top: T[w,R,D,L] (U plays D)
          float t3 = team ? tsh[w * 64 + Ri * 16 + U * 4 + Li]
                          : tsh[U * 64 + Ri * 16 + w * 4 + Li];
          acc += (double)b * (double)t3;
        }
        A[j][o] = (float)acc;
      }
      if (lane == 0) { dl[j] = lp; dr[j] = rp; }
      __syncthreads();
    }

    // ---- QR sweep left->right (MGS in registers, lane = row of M) ----
    for (int j = 0; j < NS - 1; ++j) {
      int l = dl[j], r = dr[j];
      int rows = l * 4, cols = r;
      int kq = rows < cols ? rows : cols;
      for (int o = lane; o < 256; o += 64) rw[o] = 0.0;
      double m[16];
      int li = lane >> 2, ui = lane & 3;
      bool act = lane < rows;
#pragma unroll
      for (int c = 0; c < 16; ++c)
        m[c] = (act && c < cols) ? (double)A[j][(li * r + c) * 4 + ui] : 0.0;
      __syncthreads();
#pragma unroll
      for (int c = 0; c < 16; ++c) {
        if (c < kq) {
          double n2 = wsum64(m[c] * m[c]);
          double nrm = sqrt(n2);
          double inv = (nrm > 1e-150) ? 1.0 / nrm : 0.0;
          m[c] *= inv;
          if (lane == 0) rw[c * 16 + c] = nrm;
#pragma unroll
          for (int c2 = c + 1; c2 < 16; ++c2) {
            if (c2 < cols) {
              double dt = wsum64(m[c] * m[c2]);
              m[c2] -= dt * m[c];
              if (lane == 0) rw[c * 16 + c2] = dt;
            }
          }
        }
      }
      if (act) {
#pragma unroll
        for (int c = 0; c < 16; ++c)
          if (c < kq) A[j][(li * kq + c) * 4 + ui] = (float)m[c];
      }
      if (lane == 0) dr[j] = kq;
      __syncthreads();
      // mps[j+1] = R @ mps[j+1]
      int r2 = dr[j + 1];
      int ne = cols * r2 * 4;
      for (int o = lane; o < ne; o += 64) tmp[o] = A[j + 1][o];
      __syncthreads();
      int lgr2 = 31 - __clz(r2);
      int nout = kq * r2 * 4;
      for (int o = lane; o < nout; o += 64) {
        int u2 = o & 3;
        int h = o >> 2;
        int s = h & (r2 - 1), ki = h >> lgr2;
        double acc = 0.0;
        for (int c = ki; c < cols; ++c)  // R upper-triangular
          acc += rw[ki * 16 + c] * (double)tmp[(c * r2 + s) * 4 + u2];
        A[j + 1][o] = (float)acc;
      }
      if (lane == 0) dl[j + 1] = kq;
      __syncthreads();
    }

    // ---- SVD sweep right->left with chi=4 truncation ----
    for (int j = NS - 1; j >= 1; --j) {
      int l = dl[j], r = dr[j], ru = r * 4;
      int mdim = l < ru ? l : ru;
      int k = mdim < 4 ? mdim : 4;
      bool caseA = (l <= ru);
      int d = caseA ? l : ru;
      for (int o = lane; o < 256; o += 64) gw[o] = 0.0;
      __syncthreads();
      if (caseA) {  // G = M M^T (l x l)
        int lgl = 31 - __clz(l);
        for (int idx = lane; idx < l * l; idx += 64) {
          int a = idx >> lgl, b = idx & (l - 1);
          double acc = 0.0;
          for (int t2 = 0; t2 < ru; ++t2)
            acc += (double)A[j][a * ru + t2] * (double)A[j][b * ru + t2];
          gw[a * 16 + b] = acc;
        }
      } else {      // G = M^T M (ru x ru)
        int lgru = 31 - __clz(ru);
        for (int idx = lane; idx < ru * ru; idx += 64) {
          int a = idx >> lgru, b = idx & (ru - 1);
          double acc = 0.0;
          for (int t2 = 0; t2 < l; ++t2)
            acc += (double)A[j][t2 * ru + a] * (double)A[j][t2 * ru + b];
          gw[a * 16 + b] = acc;
        }
      }
      __syncthreads();
      if (d > 4) jacobi_sym(gw, vt, ev, lane, jt16_info, jt16_PQ, 15, 12);
      else       jacobi_sym(gw, vt, ev, lane, jt4_info, jt4_PQ, 3, 8);
      __syncthreads();
      // top-k eigenpairs (redundant per lane)
      int idxs[4]; double sv[4];
      idxs[0] = idxs[1] = idxs[2] = idxs[3] = 0;
      sv[0] = sv[1] = sv[2] = sv[3] = 0.0;
      unsigned msk = 0;
#pragma unroll
      for (int t2 = 0; t2 < 4; ++t2) {
        if (t2 < k) {
          double best = -1.0; int bi = 0;
          for (int a = 0; a < 16; ++a) {
            double ea = ev[a];
            bool ok = !((msk >> a) & 1) && (ea > best);
            best = ok ? ea : best;
            bi = ok ? a : bi;
          }
          msk |= (1u << bi);
          idxs[t2] = bi;
          sv[t2] = sqrt(best > 0.0 ? best : 0.0);
        }
      }
      // Vh rows (regs) + US (LDS) computed BEFORE overwriting A[j]
      double vh[4] = {0.0, 0.0, 0.0, 0.0};
      if (caseA) {
        if (lane < ru) {
#pragma unroll
          for (int t2 = 0; t2 < 4; ++t2) if (t2 < k) {
            double acc = 0.0;
            for (int a = 0; a < l; ++a)
              acc += vt[idxs[t2] * 16 + a] * (double)A[j][a * ru + lane];
            double invs = sv[t2] > 1e-150 ? 1.0 / sv[t2] : 0.0;
            vh[t2] = acc * invs;
          }
        }
        if (lane < l) {
#pragma unroll
          for (int t2 = 0; t2 < 4; ++t2)
            usw[lane * 4 + t2] =
                (t2 < k) ? vt[idxs[t2] * 16 + lane] * sv[t2] : 0.0;
        }
      } else {
        if (lane < ru) {
#pragma unroll
          for (int t2 = 0; t2 < 4; ++t2)
            if (t2 < k) vh[t2] = vt[idxs[t2] * 16 + lane];
        }
        if (lane < l) {
#pragma unroll
          for (int t2 = 0; t2 < 4; ++t2) {
            double acc = 0.0;
            if (t2 < k)
              for (int q2 = 0; q2 < ru; ++q2)
                acc += (double)A[j][lane * ru + q2] * vt[idxs[t2] * 16 + q2];
            usw[lane * 4 + t2] = acc;
          }
        }
      }
      __syncthreads();
      if (lane < ru) {
#pragma unroll
        for (int t2 = 0; t2 < 4; ++t2)
          if (t2 < k) A[j][t2 * ru + lane] = (float)vh[t2];
      }
      if (lane == 0) dl[j] = k;
      __syncthreads();
      // mps[j-1] <- mps[j-1] @ US
      int l1 = dl[j - 1], r1 = dr[j - 1];  // r1 == l
      int ne = l1 * r1 * 4;
      for (int o = lane; o < ne; o += 64) tmp[o] = A[j - 1][o];
      __syncthreads();
      int lgk = 31 - __clz(k);
      int nout = l1 * k * 4;
      for (int o = lane; o < nout; o += 64) {
        int u2 = o & 3;
        int h = o >> 2;
        int ki = h & (k - 1), li2 = h >> lgk;
        double acc = 0.0;
        for (int m2 = 0; m2 < l; ++m2)
          acc += (double)tmp[(li2 * l + m2) * 4 + u2] * usw[m2 * 4 + ki];
        A[j - 1][o] = (float)acc;
      }
      if (lane == 0) dr[j - 1] = k;
      __syncthreads();
    }

    // ---- strip norms (equalize_norms=1.0) ----
    for (int j = 0; j < NS; ++j) {
      int nels = dl[j] * dr[j] * 4;
      double part = 0.0;
      for (int o = lane; o < nels; o += 64) {
        double x = A[j][o];
        part += x * x;
      }
      double nrm = sqrt(wsum64(part));
      double safe = nrm > 0.0 ? nrm : 1.0;
      float invs = (float)(1.0 / safe);
      for (int o = lane; o < nels; o += 64) A[j][o] *= invs;
      logZ += log(safe);
      __syncthreads();
    }
  }

  // ---- final contraction of bot & top MPS ----
  if (lane == 0) lz[team] = logZ;
  if (tid < 16) vbuf[0][tid] = (tid == 0) ? 1.0 : 0.0;
  __syncthreads();
  int cur = 0;
  for (int j = 0; j < NS; ++j) {
    if (tid < 16) {
      int adim = dL[0][j], pdim = dR[0][j];  // identical for both teams
      int pp = tid >> 2, qq = tid & 3;
      double acc = 0.0;
      if (pp < pdim && qq < pdim) {
        for (int a = 0; a < adim; ++a)
          for (int b = 0; b < adim; ++b) {
            double vab = vbuf[cur][a * 4 + b];
            double s2 = 0.0;
#pragma unroll
            for (int u = 0; u < 4; ++u)
              s2 += (double)Ash[0][j][(a * pdim + pp) * 4 + u] *
                    (double)Ash[1][j][(b * pdim + qq) * 4 + u];
            acc += vab * s2;
          }
      }
      vbuf[cur ^ 1][tid] = acc;
    }
    __syncthreads();
    cur ^= 1;
  }
  if (tid == 0) out[0] = (float)(vbuf[cur][0] * exp(lz[0] + lz[1]));
}

extern "C" void kernel_launch(void* const* d_in, const int* in_sizes, int n_in,
                              void* d_out, int out_size, void* d_ws, size_t ws_size,
                              hipStream_t stream) {
  const float* peps = (const float*)d_in[0];  // (10,10,2,4,4,4,4) fp32
  const int* xs = (const int*)d_in[1];        // (100,) int32
  float* out = (float*)d_out;                 // scalar fp32
  (void)in_sizes; (void)n_in; (void)out_size; (void)d_ws; (void)ws_size;
  amp_kernel<<<dim3(1), dim3(128), 0, stream>>>(peps, xs, out);
}

// Round 8
// 3558.943 us; speedup vs baseline: 1.5542x; 1.5542x over previous
//
#include <hip/hip_runtime.h>
#include <math.h>

// PEPS amplitude via boundary-MPS contraction, fully fused in one kernel.
// Lx=Ly=10, PHYS=2, D=4, CHI=4. Two teams (2 waves): team0 = bottom half,
// team1 = top half (identical shape sequences -> lockstep barriers).
// Decompositions (MGS-QR, Gram + XOR-scheduled parallel Jacobi) in fp64.

#define NS 10

__device__ __forceinline__ double shfl_d(double x, int src) {
  union { double d; int i[2]; } u;
  u.d = x;
  u.i[0] = __shfl(u.i[0], src, 64);
  u.i[1] = __shfl(u.i[1], src, 64);
  return u.d;
}
__device__ __forceinline__ double shflx_d(double x, int m) {
  union { double d; int i[2]; } u;
  u.d = x;
  u.i[0] = __shfl_xor(u.i[0], m, 64);
  u.i[1] = __shfl_xor(u.i[1], m, 64);
  return u.d;
}
__device__ __forceinline__ double wsum64(double x) {
#pragma unroll
  for (int o = 1; o < 64; o <<= 1) x += shflx_d(x, o);
  return x;
}
#define SEL4(a, k) ((k) == 1 ? (a)[1] : (k) == 2 ? (a)[2] : (k) == 3 ? (a)[3] : (a)[0])

// Two-sided parallel Jacobi eigensolver on a zero-padded 16x16 symmetric PSD
// matrix, XOR (hypercube) pair schedule: round d pairs {x, x^d}. Inactive /
// padded pairs self-neutralize (theta=phi=0 -> identity rotation).
// Layout: lane = i*4 + j4 holds G[i][4*j4..4*j4+3] and Vt likewise.
// No barriers inside (per-team early exit is safe).
template <int NDMAX>
__device__ void jacobi_sym_x(const double* gw, double* vtw, double* ev,
                             int lane, int maxsweep) {
  const int i = lane >> 2, j4 = lane & 3;
  double g[4], v[4];
#pragma unroll
  for (int cc = 0; cc < 4; ++cc) {
    g[cc] = gw[i * 16 + j4 * 4 + cc];
    v[cc] = (i == j4 * 4 + cc) ? 1.0 : 0.0;
  }
  for (int sw = 0; sw < maxsweep; ++sw) {
    double off = 0.0, dsq = 0.0;
#pragma unroll
    for (int cc = 0; cc < 4; ++cc) {
      double gv = g[cc];
      if (j4 * 4 + cc == i) dsq += gv * gv; else off += gv * gv;
    }
    off = wsum64(off); dsq = wsum64(dsq);
    if (off <= dsq * 1e-22) break;  // uniform across wave
#pragma unroll
    for (int d = 1; d <= NDMAX; ++d) {
      const int hb = d >= 8 ? 3 : d >= 4 ? 2 : d >= 2 ? 1 : 0;
      // my row pair {i, i^d}: t1=G[i][i], t2=G[i^d][i^d], t3=G[i][i^d]
      double dsel = SEL4(g, i & 3);                 // provider: G[row][row]
      double psel = SEL4(g, (i & 3) ^ (d & 3));     // provider: G[row][row^d]
      double t1 = shfl_d(dsel, (i << 2) + (i >> 2));
      double t3 = shfl_d(psel, (i << 2) + ((i ^ d) >> 2));
      double t2 = shfl_d(dsel, ((i ^ d) << 2) + ((i ^ d) >> 2));
      bool iq = ((i >> hb) & 1) != 0;               // I'm Q-side of my pair
      double th = iq ? (t1 - t2) : (t2 - t1);       // aqq - app
      double ph = 2.0 * t3;
      double den = fabs(th) + sqrt(th * th + ph * ph);
      double t = (den > 0.0) ? copysign(1.0, th) * ph / den : 0.0;
      double cr = rsqrt(1.0 + t * t);
      double sr = t * cr;
      // column phase: col x needs (c,s) of pair {x,x^d} and G[i][x^d]
      double oc[4], os[4], oth[4];
#pragma unroll
      for (int cc = 0; cc < 4; ++cc) {
        int col = (j4 << 2) + cc;
        int asrc = (col << 2) + (col >> 2);         // a lane of row `col`
        oc[cc] = shfl_d(cr, asrc);
        os[cc] = shfl_d(sr, asrc);
        oth[cc] = (d >> 2) ? shflx_d(g[cc ^ (d & 3)], d >> 2)
                           : g[cc ^ (d & 3)];
      }
#pragma unroll
      for (int cc = 0; cc < 4; ++cc) {
        int col = (j4 << 2) + cc;
        double sg = ((col >> hb) & 1) ? os[cc] : -os[cc];  // P side: -s
        g[cc] = oc[cc] * g[cc] + sg * oth[cc];
      }
      // row phase (+ Vt): partner row lane = lane ^ (4d)
      double og[4], ov[4];
#pragma unroll
      for (int cc = 0; cc < 4; ++cc) og[cc] = shflx_d(g[cc], d << 2);
#pragma unroll
      for (int cc = 0; cc < 4; ++cc) ov[cc] = shflx_d(v[cc], d << 2);
      double sg2 = iq ? sr : -sr;
#pragma unroll
      for (int cc = 0; cc < 4; ++cc) {
        g[cc] = cr * g[cc] + sg2 * og[cc];
        v[cc] = cr * v[cc] + sg2 * ov[cc];
      }
    }
  }
#pragma unroll
  for (int cc = 0; cc < 4; ++cc) vtw[i * 16 + j4 * 4 + cc] = v[cc];
  if ((i >> 2) == j4) ev[i] = SEL4(g, i & 3);
}

__global__ __launch_bounds__(128, 1)
void amp_kernel(const float* __restrict__ peps, const int* __restrict__ xs,
                float* __restrict__ out) {
  const int tid = threadIdx.x;
  const int team = tid >> 6;      // 0 = bottom half, 1 = top half
  const int lane = tid & 63;

  __shared__ __align__(16) float Ash[2][NS][1024];  // MPS tensors (l,r,4)
  __shared__ __align__(16) float Tmp[2][1024];      // staging
  __shared__ __align__(16) float Tsh[2][256];       // site tensor T (4,4,4,4)
  __shared__ double Rw[2][256];                     // QR R (16x16)
  __shared__ double Gw[2][256];                     // Gram (16x16, zero-pad)
  __shared__ double Vt[2][256];                     // eigvecs, Vt[idx][a]
  __shared__ double USw[2][64];                     // U[:, :k]*S[:k] (l x 4)
  __shared__ double evals[2][16];
  __shared__ int dL[2][NS], dR[2][NS];
  __shared__ double lz[2];
  __shared__ double vbuf[2][16];

  float (*A)[1024] = Ash[team];
  float* tmp = Tmp[team];
  float* tsh = Tsh[team];
  double* rw = Rw[team];
  double* gw = Gw[team];
  double* vt = Vt[team];
  double* usw = USw[team];
  double* ev = evals[team];
  int* dl = dL[team];
  int* dr = dR[team];

  double logZ = 0.0;

  // ---- init boundary row (bot: row 0, down=0; top: row 9, up=0) ----
  {
    int row0 = team ? 9 : 0;
    for (int j = 0; j < NS; ++j) {
      int p = xs[row0 * 10 + j];
      const float* tp = peps + ((size_t)(row0 * 10 + j) * 2 + p) * 256;
      ((float4*)tsh)[lane] = ((const float4*)tp)[lane];
      __syncthreads();
      int lgLt = (j == 0) ? 0 : 2, lgRt = (j == 9) ? 0 : 2;
      int Lt = 1 << lgLt, Rt = 1 << lgRt;
      int n = Lt * Rt * 4;
      if (lane < n) {
        int ui = lane & 3, h = lane >> 2;
        int ri = h & (Rt - 1), li = h >> lgRt;
        // bot: B[l,r,u] = T[u,r,0,l]; top: B[l,r,d] = T[0,r,d,l]
        float val = team ? tsh[ri * 16 + ui * 4 + li]
                         : tsh[ui * 64 + ri * 16 + li];
        A[j][lane] = val;
      }
      if (lane == 0) { dl[j] = Lt; dr[j] = Rt; }
      __syncthreads();
    }
  }

  // ---- 4 rounds of absorb + compress ----
  for (int it = 0; it < 4; ++it) {
    int row = team ? (8 - it) : (1 + it);

    // absorb row into MPS
    for (int j = 0; j < NS; ++j) {
      int p = xs[row * 10 + j];
      const float* tp = peps + ((size_t)(row * 10 + j) * 2 + p) * 256;
      ((float4*)tsh)[lane] = ((const float4*)tp)[lane];
      int l = dl[j], r = dr[j];
      int nb = l * r * 4;
      for (int o = lane; o < nb; o += 64) tmp[o] = A[j][o];
      __syncthreads();
      int lgLt = (j == 0) ? 0 : 2, lgRt = (j == 9) ? 0 : 2;
      int lp = l << lgLt, rp = r << lgRt;
      int lgrp = 31 - __clz(rp);
      int n = lp * rp * 4;
      for (int o = lane; o < n; o += 64) {
        int U = o & 3;
        int h = o >> 2;
        int ro = h & (rp - 1), lo = h >> lgrp;
        int li = lo >> lgLt, Li = lo & ((1 << lgLt) - 1);
        int ri = ro >> lgRt, Ri = ro & ((1 << lgRt) - 1);
        double acc = 0.0;
#pragma unroll
        for (int w = 0; w < 4; ++w) {
          float b = tmp[(li * r + ri) * 4 + w];
          // bot: T[U,R,w,L]; top: T[w,R,D,L] (U plays D)
          float t3 = team ? tsh[w * 64 + Ri * 16 + U * 4 + Li]
                          : tsh[U * 64 + Ri * 16 + w * 4 + Li];
          acc += (double)b * (double)t3;
        }
        A[j][o] = (float)acc;
      }
      if (lane == 0) { dl[j] = lp; dr[j] = rp; }
      __syncthreads();
    }

    // ---- QR sweep left->right (MGS in registers, lane = row of M) ----
    for (int j = 0; j < NS - 1; ++j) {
      int l = dl[j], r = dr[j];
      int rows = l * 4, cols = r;
      int kq = rows < cols ? rows : cols;
      for (int o = lane; o < 256; o += 64) rw[o] = 0.0;
      double m[16];
      int li = lane >> 2, ui = lane & 3;
      bool act = lane < rows;
#pragma unroll
      for (int c = 0; c < 16; ++c)
        m[c] = (act && c < cols) ? (double)A[j][(li * r + c) * 4 + ui] : 0.0;
      __syncthreads();
#pragma unroll
      for (int c = 0; c < 16; ++c) {
        if (c < kq) {
          double rawd[16];
          // raw dots vs the UNNORMALIZED pivot -> all wsums independent
#pragma unroll
          for (int c2 = c; c2 < 16; ++c2)
            if (c2 < cols) rawd[c2] = wsum64(m[c] * m[c2]);
          double nrm = sqrt(rawd[c]);
          double inv = (nrm > 1e-150) ? 1.0 / nrm : 0.0;
          m[c] *= inv;
          if (lane == 0) rw[c * 16 + c] = nrm;
#pragma unroll
          for (int c2 = c + 1; c2 < 16; ++c2) {
            if (c2 < cols) {
              double dt = rawd[c2] * inv;   // = <q_c, m_c2>
              m[c2] -= dt * m[c];           // m[c] now normalized
              if (lane == 0) rw[c * 16 + c2] = dt;
            }
          }
        }
      }
      if (act) {
#pragma unroll
        for (int c = 0; c < 16; ++c)
          if (c < kq) A[j][(li * kq + c) * 4 + ui] = (float)m[c];
      }
      if (lane == 0) dr[j] = kq;
      __syncthreads();
      // mps[j+1] = R @ mps[j+1]
      int r2 = dr[j + 1];
      int ne = cols * r2 * 4;
      for (int o = lane; o < ne; o += 64) tmp[o] = A[j + 1][o];
      __syncthreads();
      int lgr2 = 31 - __clz(r2);
      int nout = kq * r2 * 4;
      for (int o = lane; o < nout; o += 64) {
        int u2 = o & 3;
        int h = o >> 2;
        int s = h & (r2 - 1), ki = h >> lgr2;
        double acc = 0.0;
        for (int c = ki; c < cols; ++c)  // R upper-triangular
          acc += rw[ki * 16 + c] * (double)tmp[(c * r2 + s) * 4 + u2];
        A[j + 1][o] = (float)acc;
      }
      if (lane == 0) dl[j + 1] = kq;
      __syncthreads();
    }

    // ---- SVD sweep right->left with chi=4 truncation ----
    for (int j = NS - 1; j >= 1; --j) {
      int l = dl[j], r = dr[j], ru = r * 4;
      int mdim = l < ru ? l : ru;
      int k = mdim < 4 ? mdim : 4;
      bool caseA = (l <= ru);
      int d = caseA ? l : ru;
      for (int o = lane; o < 256; o += 64) gw[o] = 0.0;
      __syncthreads();
      if (caseA) {  // G = M M^T (l x l)
        int lgl = 31 - __clz(l);
        for (int idx = lane; idx < l * l; idx += 64) {
          int a = idx >> lgl, b = idx & (l - 1);
          double acc = 0.0;
          for (int t2 = 0; t2 < ru; ++t2)
            acc += (double)A[j][a * ru + t2] * (double)A[j][b * ru + t2];
          gw[a * 16 + b] = acc;
        }
      } else {      // G = M^T M (ru x ru)
        int lgru = 31 - __clz(ru);
        for (int idx = lane; idx < ru * ru; idx += 64) {
          int a = idx >> lgru, b = idx & (ru - 1);
          double acc = 0.0;
          for (int t2 = 0; t2 < l; ++t2)
            acc += (double)A[j][t2 * ru + a] * (double)A[j][t2 * ru + b];
          gw[a * 16 + b] = acc;
        }
      }
      __syncthreads();
      if (d > 4) jacobi_sym_x<15>(gw, vt, ev, lane, 10);
      else       jacobi_sym_x<3>(gw, vt, ev, lane, 6);
      __syncthreads();
      // top-k eigenpairs (redundant per lane)
      int idxs[4]; double sv[4];
      idxs[0] = idxs[1] = idxs[2] = idxs[3] = 0;
      sv[0] = sv[1] = sv[2] = sv[3] = 0.0;
      unsigned msk = 0;
#pragma unroll
      for (int t2 = 0; t2 < 4; ++t2) {
        if (t2 < k) {
          double best = -1.0; int bi = 0;
          for (int a = 0; a < 16; ++a) {
            double ea = ev[a];
            bool ok = !((msk >> a) & 1) && (ea > best);
            best = ok ? ea : best;
            bi = ok ? a : bi;
          }
          msk |= (1u << bi);
          idxs[t2] = bi;
          sv[t2] = sqrt(best > 0.0 ? best : 0.0);
        }
      }
      // Vh rows (regs) + US (LDS) computed BEFORE overwriting A[j]
      double vh[4] = {0.0, 0.0, 0.0, 0.0};
      if (caseA) {
        if (lane < ru) {
#pragma unroll
          for (int t2 = 0; t2 < 4; ++t2) if (t2 < k) {
            double acc = 0.0;
            for (int a = 0; a < l; ++a)
              acc += vt[idxs[t2] * 16 + a] * (double)A[j][a * ru + lane];
            double invs = sv[t2] > 1e-150 ? 1.0 / sv[t2] : 0.0;
            vh[t2] = acc * invs;
          }
        }
        if (lane < l) {
#pragma unroll
          for (int t2 = 0; t2 < 4; ++t2)
            usw[lane * 4 + t2] =
                (t2 < k) ? vt[idxs[t2] * 16 + lane] * sv[t2] : 0.0;
        }
      } else {
        if (lane < ru) {
#pragma unroll
          for (int t2 = 0; t2 < 4; ++t2)
            if (t2 < k) vh[t2] = vt[idxs[t2] * 16 + lane];
        }
        if (lane < l) {
#pragma unroll
          for (int t2 = 0; t2 < 4; ++t2) {
            double acc = 0.0;
            if (t2 < k)
              for (int q2 = 0; q2 < ru; ++q2)
                acc += (double)A[j][lane * ru + q2] * vt[idxs[t2] * 16 + q2];
            usw[lane * 4 + t2] = acc;
          }
        }
      }
      __syncthreads();
      if (lane < ru) {
#pragma unroll
        for (int t2 = 0; t2 < 4; ++t2)
          if (t2 < k) A[j][t2 * ru + lane] = (float)vh[t2];
      }
      if (lane == 0) dl[j] = k;
      __syncthreads();
      // mps[j-1] <- mps[j-1] @ US
      int l1 = dl[j - 1], r1 = dr[j - 1];  // r1 == l
      int ne = l1 * r1 * 4;
      for (int o = lane; o < ne; o += 64) tmp[o] = A[j - 1][o];
      __syncthreads();
      int lgk = 31 - __clz(k);
      int nout = l1 * k * 4;
      for (int o = lane; o < nout; o += 64) {
        int u2 = o & 3;
        int h = o >> 2;
        int ki = h & (k - 1), li2 = h >> lgk;
        double acc = 0.0;
        for (int m2 = 0; m2 < l; ++m2)
          acc += (double)tmp[(li2 * l + m2) * 4 + u2] * usw[m2 * 4 + ki];
        A[j - 1][o] = (float)acc;
      }
      if (lane == 0) dr[j - 1] = k;
      __syncthreads();
    }

    // ---- strip norms (equalize_norms=1.0) ----
    for (int j = 0; j < NS; ++j) {
      int nels = dl[j] * dr[j] * 4;
      double part = 0.0;
      for (int o = lane; o < nels; o += 64) {
        double x = A[j][o];
        part += x * x;
      }
      double nrm = sqrt(wsum64(part));
      double safe = nrm > 0.0 ? nrm : 1.0;
      float invs = (float)(1.0 / safe);
      for (int o = lane; o < nels; o += 64) A[j][o] *= invs;
      logZ += log(safe);
      __syncthreads();
    }
  }

  // ---- final contraction of bot & top MPS ----
  if (lane == 0) lz[team] = logZ;
  if (tid < 16) vbuf[0][tid] = (tid == 0) ? 1.0 : 0.0;
  __syncthreads();
  int cur = 0;
  for (int j = 0; j < NS; ++j) {
    if (tid < 16) {
      int adim = dL[0][j], pdim = dR[0][j];  // identical for both teams
      int pp = tid >> 2, qq = tid & 3;
      double acc = 0.0;
      if (pp < pdim && qq < pdim) {
        for (int a = 0; a < adim; ++a)
          for (int b = 0; b < adim; ++b) {
            double vab = vbuf[cur][a * 4 + b];
            double s2 = 0.0;
#pragma unroll
            for (int u = 0; u < 4; ++u)
              s2 += (double)Ash[0][j][(a * pdim + pp) * 4 + u] *
                    (double)Ash[1][j][(b * pdim + qq) * 4 + u];
            acc += vab * s2;
          }
      }
      vbuf[cur ^ 1][tid] = acc;
    }
    __syncthreads();
    cur ^= 1;
  }
  if (tid == 0) out[0] = (float)(vbuf[cur][0] * exp(lz[0] + lz[1]));
}

extern "C" void kernel_launch(void* const* d_in, const int* in_sizes, int n_in,
                              void* d_out, int out_size, void* d_ws, size_t ws_size,
                              hipStream_t stream) {
  const float* peps = (const float*)d_in[0];  // (10,10,2,4,4,4,4) fp32
  const int* xs = (const int*)d_in[1];        // (100,) int32
  float* out = (float*)d_out;                 // scalar fp32
  (void)in_sizes; (void)n_in; (void)out_size; (void)d_ws; (void)ws_size;
  amp_kernel<<<dim3(1), dim3(128), 0, stream>>>(peps, xs, out);
}